// Round 1
// baseline (486.762 us; speedup 1.0000x reference)
//
#include <hip/hip_runtime.h>
#include <hip/hip_bf16.h>

#define N_NODES 50000
#define N_EDGES 800000
// DIN=DOUT=64, DIM=3, K=8

// ---------- helpers ----------
__device__ __forceinline__ void store_val(float* p, float v) { *p = v; }
__device__ __forceinline__ void store_val(__hip_bfloat16* p, float v) { *p = __float2bfloat16(v); }
__device__ __forceinline__ float load_val(const float* p) { return *p; }
__device__ __forceinline__ float load_val(const __hip_bfloat16* p) { return __bfloat162float(*p); }

// ---------- 0. precompute -0.5/(sigma^2+eps) ----------
__global__ void prep_c1_kernel(const float* __restrict__ sigma, float* __restrict__ c1) {
    int i = threadIdx.x;
    if (i < 24) {
        float s = sigma[i];
        c1[i] = -0.5f / (s * s + 1e-15f);
    }
}

// ---------- 1. x_trans = x @ W_g  (50000x64 @ 64x512) ----------
// block: 256 thr, 16 rows per block. Each thread: 2 cols (tid, tid+256) x 16 rows.
template <typename T>
__global__ void gemm_xt_kernel(const float* __restrict__ x, const float* __restrict__ Wg,
                               T* __restrict__ xt) {
    __shared__ float xs[16][64];
    const int tid = threadIdx.x;
    const int row0 = blockIdx.x << 4;
    for (int i = tid; i < 1024; i += 256) xs[i >> 6][i & 63] = x[(size_t)row0 * 64 + i];
    __syncthreads();

    float acc0[16], acc1[16];
#pragma unroll
    for (int r = 0; r < 16; r++) { acc0[r] = 0.f; acc1[r] = 0.f; }

#pragma unroll 4
    for (int i = 0; i < 64; i++) {
        float w0 = Wg[i * 512 + tid];
        float w1 = Wg[i * 512 + tid + 256];
#pragma unroll
        for (int r = 0; r < 16; r++) {
            float xv = xs[r][i];
            acc0[r] = fmaf(xv, w0, acc0[r]);
            acc1[r] = fmaf(xv, w1, acc1[r]);
        }
    }
#pragma unroll
    for (int r = 0; r < 16; r++) {
        size_t o = ((size_t)(row0 + r)) * 512 + tid;
        store_val(&xt[o], acc0[r]);
        store_val(&xt[o + 256], acc1[r]);
    }
}

// ---------- 2. edge kernel: gauss -> gather -> msg -> atomic scatter ----------
// one 64-lane wave per edge; lane = output channel
template <typename T>
__global__ void edge_kernel(const int* __restrict__ eidx, const float* __restrict__ eattr,
                            const float* __restrict__ mu, const float* __restrict__ c1,
                            const T* __restrict__ xt, float* __restrict__ agg,
                            float* __restrict__ cnt) {
    __shared__ float smu[24], sc1[24];
    const int tid = threadIdx.x;
    if (tid < 24) smu[tid] = mu[tid];
    else if (tid < 48) sc1[tid - 24] = c1[tid - 24];
    __syncthreads();

    const int e = (blockIdx.x << 2) + (tid >> 6);
    const int lane = tid & 63;

    const int src = eidx[e];
    const int dst = eidx[N_EDGES + e];

    const float a0 = eattr[e * 3 + 0];
    const float a1 = eattr[e * 3 + 1];
    const float a2 = eattr[e * 3 + 2];

    // each 8-lane group computes one gaussian; broadcast via shfl
    const int kk = lane & 7;
    const float d0 = a0 - smu[kk * 3 + 0];
    const float d1 = a1 - smu[kk * 3 + 1];
    const float d2 = a2 - smu[kk * 3 + 2];
    const float gv = __expf(fmaf(d0 * d0, sc1[kk * 3 + 0],
                            fmaf(d1 * d1, sc1[kk * 3 + 1],
                                 d2 * d2 * sc1[kk * 3 + 2])));

    const T* xr = xt + (size_t)src * 512 + lane;
    float xv[8];
#pragma unroll
    for (int k = 0; k < 8; k++) xv[k] = load_val(&xr[k * 64]);

    float v = 0.f;
#pragma unroll
    for (int k = 0; k < 8; k++) {
        float gk = __shfl(gv, k, 64);
        v = fmaf(gk, xv[k], v);
    }

    atomicAdd(&agg[(size_t)dst * 64 + lane], v);
    if (lane == 0) atomicAdd(&cnt[dst], 1.0f);
}

// ---------- 3. root GEMM + bias + mean-aggregate + BN stat partials ----------
__global__ void root_stats_kernel(const float* __restrict__ x, const float* __restrict__ Wr,
                                  const float* __restrict__ bias, const float* __restrict__ agg,
                                  const float* __restrict__ cnt, float* __restrict__ out_pre,
                                  double* __restrict__ colsum, double* __restrict__ colsumsq) {
    __shared__ float wr[4096];
    __shared__ float rs[256], rsq[256];
    for (int i = threadIdx.x; i < 4096; i += 256) wr[i] = Wr[i];
    __syncthreads();

    const int wave = threadIdx.x >> 6;
    const int lane = threadIdx.x & 63;
    const float b = bias[lane];
    const int stride = gridDim.x * 4;

    float s = 0.f, sq = 0.f;
    for (int n = blockIdx.x * 4 + wave; n < N_NODES; n += stride) {
        float xv = x[(size_t)n * 64 + lane];
        float acc = 0.f;
#pragma unroll
        for (int i = 0; i < 64; i++)
            acc = fmaf(__shfl(xv, i, 64), wr[i * 64 + lane], acc);
        float c = cnt[n];
        float val = agg[(size_t)n * 64 + lane] / fmaxf(c, 1.f) + acc + b;
        out_pre[(size_t)n * 64 + lane] = val;
        s += val;
        sq += val * val;
    }

    rs[threadIdx.x] = s;
    rsq[threadIdx.x] = sq;
    __syncthreads();
    if (threadIdx.x < 64) {
        float ts = rs[threadIdx.x] + rs[threadIdx.x + 64] + rs[threadIdx.x + 128] + rs[threadIdx.x + 192];
        float tq = rsq[threadIdx.x] + rsq[threadIdx.x + 64] + rsq[threadIdx.x + 128] + rsq[threadIdx.x + 192];
        atomicAdd(&colsum[threadIdx.x], (double)ts);
        atomicAdd(&colsumsq[threadIdx.x], (double)tq);
    }
}

// ---------- 4. finalize BN params ----------
__global__ void bn_prep_kernel(const double* __restrict__ colsum, const double* __restrict__ colsumsq,
                               float* __restrict__ meanr) {
    int c = threadIdx.x;
    if (c < 64) {
        double m = colsum[c] / (double)N_NODES;
        double var = colsumsq[c] / (double)N_NODES - m * m;
        meanr[c] = (float)m;
        meanr[64 + c] = (float)(1.0 / sqrt(var + 1e-5));
    }
}

// ---------- 5. BN apply + LeakyReLU (in-place on d_out) ----------
__global__ void finalize_kernel(float* __restrict__ out, const float* __restrict__ meanr,
                                const float* __restrict__ gamma, const float* __restrict__ beta) {
    const int i = blockIdx.x * 256 + threadIdx.x;
    const int c = i & 63;
    float v = out[i];
    float o = fmaf((v - meanr[c]) * meanr[64 + c], gamma[c], beta[c]);
    out[i] = o > 0.f ? o : 0.01f * o;
}

extern "C" void kernel_launch(void* const* d_in, const int* in_sizes, int n_in,
                              void* d_out, int out_size, void* d_ws, size_t ws_size,
                              hipStream_t stream) {
    const float* x     = (const float*)d_in[0];
    const int*   eidx  = (const int*)d_in[1];
    const float* eattr = (const float*)d_in[2];
    const float* Wg    = (const float*)d_in[3];
    const float* mu    = (const float*)d_in[4];
    const float* sigma = (const float*)d_in[5];
    const float* Wr    = (const float*)d_in[6];
    const float* bias  = (const float*)d_in[7];
    const float* gamma = (const float*)d_in[8];
    const float* beta  = (const float*)d_in[9];
    float* out = (float*)d_out;

    char* ws = (char*)d_ws;
    const size_t agg_off     = 0;
    const size_t cnt_off     = agg_off + (size_t)N_NODES * 64 * 4;   // 12,800,000
    const size_t colsum_off  = cnt_off + (size_t)N_NODES * 4;        // +200,000
    const size_t colsumsq_off = colsum_off + 64 * 8;
    const size_t meanr_off   = colsumsq_off + 64 * 8;
    const size_t c1_off      = meanr_off + 128 * 4;
    const size_t xt_off      = c1_off + 128;                          // 64B-aligned
    const size_t zero_bytes  = colsumsq_off + 512;                    // agg..colsumsq

    float*  agg      = (float*)(ws + agg_off);
    float*  cnt      = (float*)(ws + cnt_off);
    double* colsum   = (double*)(ws + colsum_off);
    double* colsumsq = (double*)(ws + colsumsq_off);
    float*  meanr    = (float*)(ws + meanr_off);
    float*  c1       = (float*)(ws + c1_off);

    hipMemsetAsync(ws + agg_off, 0, zero_bytes, stream);
    prep_c1_kernel<<<1, 32, 0, stream>>>(sigma, c1);

    const bool f32path = ws_size >= xt_off + (size_t)N_NODES * 512 * 4;
    if (f32path) {
        float* xt = (float*)(ws + xt_off);
        gemm_xt_kernel<float><<<N_NODES / 16, 256, 0, stream>>>(x, Wg, xt);
        edge_kernel<float><<<N_EDGES / 4, 256, 0, stream>>>(eidx, eattr, mu, c1, xt, agg, cnt);
    } else {
        __hip_bfloat16* xt = (__hip_bfloat16*)(ws + xt_off);
        gemm_xt_kernel<__hip_bfloat16><<<N_NODES / 16, 256, 0, stream>>>(x, Wg, xt);
        edge_kernel<__hip_bfloat16><<<N_EDGES / 4, 256, 0, stream>>>(eidx, eattr, mu, c1, xt, agg, cnt);
    }

    root_stats_kernel<<<1024, 256, 0, stream>>>(x, Wr, bias, agg, cnt, out, colsum, colsumsq);
    bn_prep_kernel<<<1, 64, 0, stream>>>(colsum, colsumsq, meanr);
    finalize_kernel<<<(N_NODES * 64) / 256, 256, 0, stream>>>(out, meanr, gamma, beta);
}